// Round 1
// baseline (943.863 us; speedup 1.0000x reference)
//
#include <hip/hip_runtime.h>
#include <stdint.h>

#define ALPHA_ 1.0f
#define BETA_ 0.25f
#define NUM_EMBEDS 8192
#define EMBED_DIM 512
#define B_ 32
#define T_ 256
#define N_TOK (B_ * T_)  // 8192

// ---------------- ws layout ----------------
// [0,      65536)  : unsigned long long wmin[8192]   (packed min: key<<32 | idx)
// [65536,  98304)  : float cnorm[8192]
// [98304, 131072)  : int counts[8192]
// [131072,131076)  : float sse
// -------------------------------------------

__global__ void cnorm_kernel(const float* __restrict__ cb, float* __restrict__ cnorm) {
    int row = blockIdx.x * 4 + (threadIdx.x >> 6);
    int lane = threadIdx.x & 63;
    const float4* p = (const float4*)(cb + (size_t)row * EMBED_DIM);
    float4 v0 = p[lane * 2], v1 = p[lane * 2 + 1];
    float s = v0.x * v0.x + v0.y * v0.y + v0.z * v0.z + v0.w * v0.w +
              v1.x * v1.x + v1.y * v1.y + v1.z * v1.z + v1.w * v1.w;
    for (int m = 32; m; m >>= 1) s += __shfl_xor(s, m, 64);
    if (lane == 0) cnorm[row] = s;
}

#define TN 128
#define TK 128
#define DK 16
#define KSPLIT 8
#define KCHUNK (NUM_EMBEDS / KSPLIT)  // 1024

// score(n,k) = ||c_k||^2 - 2 * z_n . c_k   (argmin-equivalent to full sq dist)
__global__ __launch_bounds__(256) void argmin_kernel(
    const float* __restrict__ z, const float* __restrict__ cb,
    const float* __restrict__ cnorm, unsigned long long* __restrict__ wmin) {
    __shared__ float As[DK][TN];
    __shared__ float Bs[DK][TK];
    const int tid = threadIdx.x;
    const int tx = tid & 15, ty = tid >> 4;
    const int n0 = blockIdx.x * TN;
    const int b = n0 >> 8;    // n0 / T_
    const int t0 = n0 & 255;  // n0 % T_
    const int kbase = blockIdx.y * KCHUNK;

    float bestv[8];
    unsigned int besti[8];
#pragma unroll
    for (int i = 0; i < 8; i++) { bestv[i] = 3.4e38f; besti[i] = 0u; }

    // z[b, d, t] = z[((b*512)+d)*256 + t]
    const float* zb = z + ((size_t)b * EMBED_DIM) * T_ + t0;

    for (int kt = 0; kt < KCHUNK; kt += TK) {
        float acc[8][8];
#pragma unroll
        for (int i = 0; i < 8; i++)
#pragma unroll
            for (int j = 0; j < 8; j++) acc[i][j] = 0.f;

        for (int d0 = 0; d0 < EMBED_DIM; d0 += DK) {
            // stage A tile: 16 d-rows x 128 tokens (coalesced along t)
            {
                int toff = (tid & 31) * 4;
                int dl = tid >> 5;  // 0..7
#pragma unroll
                for (int rr = 0; rr < 2; rr++) {
                    int dd = dl + rr * 8;
                    float4 v = *(const float4*)(zb + (size_t)(d0 + dd) * T_ + toff);
                    *(float4*)&As[dd][toff] = v;
                }
            }
            // stage B tile transposed: codebook rows -> Bs[d][k]
            {
                int doff = (tid & 3) * 4;
                int kk = tid >> 2;  // 0..63
#pragma unroll
                for (int rr = 0; rr < 2; rr++) {
                    int kcur = kk + rr * 64;
                    float4 v = *(const float4*)(cb + (size_t)(kbase + kt + kcur) * EMBED_DIM + d0 + doff);
                    Bs[doff + 0][kcur] = v.x;
                    Bs[doff + 1][kcur] = v.y;
                    Bs[doff + 2][kcur] = v.z;
                    Bs[doff + 3][kcur] = v.w;
                }
            }
            __syncthreads();
#pragma unroll
            for (int r = 0; r < DK; r++) {
                float a[8], bb[8];
                *(float4*)&a[0] = *(const float4*)&As[r][ty * 4];
                *(float4*)&a[4] = *(const float4*)&As[r][64 + ty * 4];
                *(float4*)&bb[0] = *(const float4*)&Bs[r][tx * 4];
                *(float4*)&bb[4] = *(const float4*)&Bs[r][64 + tx * 4];
#pragma unroll
                for (int i = 0; i < 8; i++)
#pragma unroll
                    for (int j = 0; j < 8; j++) acc[i][j] += a[i] * bb[j];
            }
            __syncthreads();
        }
        // fold tile into running best (k strictly increasing -> '<' keeps first-min)
#pragma unroll
        for (int j = 0; j < 8; j++) {
            int kl = (j < 4) ? (tx * 4 + j) : (64 + tx * 4 + (j - 4));
            unsigned int k = (unsigned int)(kbase + kt + kl);
            float cn = cnorm[k];
#pragma unroll
            for (int i = 0; i < 8; i++) {
                float s = cn - 2.0f * acc[i][j];
                if (s < bestv[i]) { bestv[i] = s; besti[i] = k; }
            }
        }
    }
    // reduce across the 16 tx lanes sharing each token row
#pragma unroll
    for (int i = 0; i < 8; i++) {
        float v = bestv[i];
        unsigned int ix = besti[i];
        for (int m = 1; m < 16; m <<= 1) {
            float ov = __shfl_xor(v, m, 16);
            unsigned int oi = (unsigned int)__shfl_xor((int)ix, m, 16);
            if (ov < v || (ov == v && oi < ix)) { v = ov; ix = oi; }
        }
        if (tx == 0) {
            int tok = ty * 4 + (i & 3) + ((i >> 2) << 6);
            unsigned int u = __float_as_uint(v);
            u = (u & 0x80000000u) ? ~u : (u | 0x80000000u);  // monotonic float key
            unsigned long long packed = ((unsigned long long)u << 32) | (unsigned long long)ix;
            atomicMin(&wmin[n0 + tok], packed);
        }
    }
}

__global__ void gather_kernel(const float* __restrict__ z, const float* __restrict__ cb,
                              const unsigned long long* __restrict__ wmin,
                              float* __restrict__ out, int* __restrict__ counts,
                              float* __restrict__ sse_acc) {
    __shared__ unsigned int sIdx[64];
    __shared__ float red[4];
    const int tid = threadIdx.x;
    const int n0 = blockIdx.x * 64;
    const int b = n0 >> 8;
    const int t0 = n0 & 255;
    if (tid < 64) {
        unsigned int idx = (unsigned int)(wmin[n0 + tid] & 0xffffffffULL);
        sIdx[tid] = idx;
        atomicAdd(&counts[idx], 1);
    }
    __syncthreads();
    const int w = tid >> 6;
    const int lane = tid & 63;
    const float* crow = cb + (size_t)sIdx[lane] * EMBED_DIM;
    const size_t base = ((size_t)b * EMBED_DIM) * T_ + (size_t)(t0 + lane);
    float sse = 0.f;
    for (int d = w; d < EMBED_DIM; d += 4) {
        float v = crow[d];
        size_t o = base + (size_t)d * T_;
        float diff = v - z[o];
        out[o] = v;  // z + sg(z_q - z) == z_q numerically
        sse += diff * diff;
    }
    for (int m = 32; m; m >>= 1) sse += __shfl_xor(sse, m, 64);
    if (lane == 0) red[w] = sse;
    __syncthreads();
    if (tid == 0) atomicAdd(sse_acc, red[0] + red[1] + red[2] + red[3]);
}

__global__ void finalize_kernel(const int* __restrict__ counts,
                                const float* __restrict__ sse_acc,
                                float* __restrict__ out) {
    __shared__ float red[4];
    const int tid = threadIdx.x;
    float e = 0.f;
    for (int k = tid; k < NUM_EMBEDS; k += 256) {
        float p = (float)counts[k] * (1.0f / (float)N_TOK);
        e += p * logf(p + 1e-10f);
    }
    for (int m = 32; m; m >>= 1) e += __shfl_xor(e, m, 64);
    if ((tid & 63) == 0) red[tid >> 6] = e;
    __syncthreads();
    if (tid == 0) {
        float ent = red[0] + red[1] + red[2] + red[3];
        size_t off = (size_t)B_ * EMBED_DIM * T_;
        out[off + 0] = (ALPHA_ * BETA_) * sse_acc[0] / (float)((size_t)N_TOK * EMBED_DIM);
        out[off + 1] = expf(-ent);
    }
}

extern "C" void kernel_launch(void* const* d_in, const int* in_sizes, int n_in,
                              void* d_out, int out_size, void* d_ws, size_t ws_size,
                              hipStream_t stream) {
    const float* z = (const float*)d_in[0];
    const float* cb = (const float*)d_in[1];
    float* out = (float*)d_out;
    char* ws = (char*)d_ws;
    unsigned long long* wmin = (unsigned long long*)ws;
    float* cnorm = (float*)(ws + 65536);
    int* counts = (int*)(ws + 98304);
    float* sse = (float*)(ws + 131072);

    hipMemsetAsync(wmin, 0xFF, NUM_EMBEDS * sizeof(unsigned long long), stream);
    hipMemsetAsync(counts, 0, NUM_EMBEDS * sizeof(int) + sizeof(float), stream);  // counts + sse

    cnorm_kernel<<<NUM_EMBEDS / 4, 256, 0, stream>>>(cb, cnorm);
    argmin_kernel<<<dim3(N_TOK / TN, KSPLIT), 256, 0, stream>>>(z, cb, cnorm, wmin);
    gather_kernel<<<N_TOK / 64, 256, 0, stream>>>(z, cb, wmin, out, counts, sse);
    finalize_kernel<<<1, 256, 0, stream>>>(counts, sse, out);
}

// Round 2
// 435.585 us; speedup vs baseline: 2.1669x; 2.1669x over previous
//
#include <hip/hip_runtime.h>
#include <stdint.h>

typedef _Float16 half8 __attribute__((ext_vector_type(8)));
typedef float floatx16 __attribute__((ext_vector_type(16)));

#define ALPHA_ 1.0f
#define BETA_ 0.25f
#define NUM_EMBEDS 8192
#define EMBED_DIM 512
#define B_ 32
#define T_ 256
#define N_TOK (B_ * T_)  // 8192

// ---------------- ws layout ----------------
// [0,      65536)  : unsigned long long wmin[8192]   (packed min: key<<32 | idx)
// [65536,  98304)  : float cnorm[8192]
// [98304, 131072)  : int counts[8192]
// [131072,131076)  : float sse
// -------------------------------------------

__global__ void cnorm_kernel(const float* __restrict__ cb, float* __restrict__ cnorm) {
    int row = blockIdx.x * 4 + (threadIdx.x >> 6);
    int lane = threadIdx.x & 63;
    const float4* p = (const float4*)(cb + (size_t)row * EMBED_DIM);
    float4 v0 = p[lane * 2], v1 = p[lane * 2 + 1];
    float s = v0.x * v0.x + v0.y * v0.y + v0.z * v0.z + v0.w * v0.w +
              v1.x * v1.x + v1.y * v1.y + v1.z * v1.z + v1.w * v1.w;
    for (int m = 32; m; m >>= 1) s += __shfl_xor(s, m, 64);
    if (lane == 0) cnorm[row] = s;
}

// ---- f16 2-plane argmin GEMM ----
#define TK_BLK 128   // codes per block tile (MFMA M)
#define TN_BLK 128   // tokens per block tile (MFMA N)
#define KCHUNK 1024
#define NCOL (KCHUNK / TK_BLK)            // 8
#define KSPLIT (NUM_EMBEDS / KCHUNK)      // 8
#define RS 20        // LDS row stride in u32 (16 data + 4 pad) = 80 B, 16B aligned

// pack fp32 -> (h = f16(x)) | (m = f16((x-h)*2048)) << 16
__device__ __forceinline__ uint32_t pack2(float x) {
    _Float16 h = (_Float16)x;
    float hf = (float)h;
    _Float16 m = (_Float16)((x - hf) * 2048.0f);
    return (uint32_t)__builtin_bit_cast(unsigned short, h) |
           ((uint32_t)__builtin_bit_cast(unsigned short, m) << 16);
}

union H8 { uint32_t u[4]; half8 h; };

__device__ __forceinline__ void unpack_frag(const uint32_t* p, half8& hh, half8& mm) {
    uint4 u0 = *(const uint4*)p;
    uint4 u1 = *(const uint4*)(p + 4);
    H8 a, b;
    a.u[0] = __builtin_amdgcn_perm(u0.y, u0.x, 0x05040100u);
    a.u[1] = __builtin_amdgcn_perm(u0.w, u0.z, 0x05040100u);
    a.u[2] = __builtin_amdgcn_perm(u1.y, u1.x, 0x05040100u);
    a.u[3] = __builtin_amdgcn_perm(u1.w, u1.z, 0x05040100u);
    b.u[0] = __builtin_amdgcn_perm(u0.y, u0.x, 0x07060302u);
    b.u[1] = __builtin_amdgcn_perm(u0.w, u0.z, 0x07060302u);
    b.u[2] = __builtin_amdgcn_perm(u1.y, u1.x, 0x07060302u);
    b.u[3] = __builtin_amdgcn_perm(u1.w, u1.z, 0x07060302u);
    hh = a.h; mm = b.h;
}

__global__ __launch_bounds__(256, 2) void argmin_kernel(
    const float* __restrict__ z, const float* __restrict__ cb,
    const float* __restrict__ cnorm, unsigned long long* __restrict__ wmin) {
    __shared__ uint32_t As[TK_BLK * RS];  // codebook (h|m) packed, [code][k]
    __shared__ uint32_t Bs[TN_BLK * RS];  // -2*z (h|m) packed, [token][k]
    const int tid = threadIdx.x;
    const int lane = tid & 63;
    const int wv = tid >> 6;
    const int wp = wv >> 1;   // code-half of block tile
    const int wq = wv & 1;    // token-half
    const int l31 = lane & 31;
    const int half = lane >> 5;

    const int n0 = blockIdx.x * TN_BLK;
    const int bb = n0 >> 8;    // batch (T_=256, TN_BLK=128 -> same batch per block)
    const int t0 = n0 & 255;
    const int kbase = blockIdx.y * KCHUNK;

    // staging assignments
    const int a_code = tid >> 1;          // 0..127
    const int a_dh = tid & 1;             // which 8-k half
    const int b_t = tid & 127;            // token in block
    const int b_dgrp = tid >> 7;          // which 8-d group

    unsigned long long best[2] = {~0ULL, ~0ULL};

    for (int col = 0; col < NCOL; ++col) {
        const int kb = kbase + col * TK_BLK;
        floatx16 acc1[2][2], acc2[2][2];
#pragma unroll
        for (int pi = 0; pi < 2; ++pi)
#pragma unroll
            for (int qi = 0; qi < 2; ++qi)
#pragma unroll
                for (int r = 0; r < 16; ++r) { acc1[pi][qi][r] = 0.0f; acc2[pi][qi][r] = 0.0f; }

        for (int step = 0; step < 33; ++step) {
            const int d0 = step * 16;
            uint32_t apack[8], bpack[8];
            if (step < 32) {
                // A: codebook row slice, contiguous
                const float* srcA = cb + (size_t)(kb + a_code) * EMBED_DIM + d0 + a_dh * 8;
                float4 v0 = *(const float4*)srcA;
                float4 v1 = *(const float4*)(srcA + 4);
                apack[0] = pack2(v0.x); apack[1] = pack2(v0.y);
                apack[2] = pack2(v0.z); apack[3] = pack2(v0.w);
                apack[4] = pack2(v1.x); apack[5] = pack2(v1.y);
                apack[6] = pack2(v1.z); apack[7] = pack2(v1.w);
                // B: z (b,d,t) -> transpose in regs, scale by -2
                const float* srcB = z + ((size_t)bb * EMBED_DIM + d0 + b_dgrp * 8) * T_ + t0 + b_t;
#pragma unroll
                for (int j = 0; j < 8; ++j)
                    bpack[j] = pack2(-2.0f * srcB[(size_t)j * T_]);
            } else {
                // extra K-step: inject ||c||^2 (2-plane) vs B=1.0
#pragma unroll
                for (int j = 0; j < 8; ++j) { apack[j] = 0u; bpack[j] = 0u; }
                if (a_dh == 0) apack[0] = pack2(cnorm[kb + a_code]);
                if (b_dgrp == 0) bpack[0] = 0x00003C00u;  // h=1.0f16, m=0
            }
            __syncthreads();  // previous step's LDS reads done
            *(uint4*)&As[a_code * RS + a_dh * 8 + 0] = make_uint4(apack[0], apack[1], apack[2], apack[3]);
            *(uint4*)&As[a_code * RS + a_dh * 8 + 4] = make_uint4(apack[4], apack[5], apack[6], apack[7]);
            *(uint4*)&Bs[b_t * RS + b_dgrp * 8 + 0] = make_uint4(bpack[0], bpack[1], bpack[2], bpack[3]);
            *(uint4*)&Bs[b_t * RS + b_dgrp * 8 + 4] = make_uint4(bpack[4], bpack[5], bpack[6], bpack[7]);
            __syncthreads();  // writes visible

            half8 Ah[2], Am[2], Bh[2], Bm[2];
#pragma unroll
            for (int pi = 0; pi < 2; ++pi)
                unpack_frag(&As[(wp * 64 + pi * 32 + l31) * RS + half * 8], Ah[pi], Am[pi]);
#pragma unroll
            for (int qi = 0; qi < 2; ++qi)
                unpack_frag(&Bs[(wq * 64 + qi * 32 + l31) * RS + half * 8], Bh[qi], Bm[qi]);
#pragma unroll
            for (int pi = 0; pi < 2; ++pi)
#pragma unroll
                for (int qi = 0; qi < 2; ++qi) {
                    acc1[pi][qi] = __builtin_amdgcn_mfma_f32_32x32x16_f16(Ah[pi], Bh[qi], acc1[pi][qi], 0, 0, 0);
                    acc2[pi][qi] = __builtin_amdgcn_mfma_f32_32x32x16_f16(Ah[pi], Bm[qi], acc2[pi][qi], 0, 0, 0);
                    acc2[pi][qi] = __builtin_amdgcn_mfma_f32_32x32x16_f16(Am[pi], Bh[qi], acc2[pi][qi], 0, 0, 0);
                }
        }  // step

        // fold this col-chunk into running per-token best (in-lane: regs are codes)
#pragma unroll
        for (int qi = 0; qi < 2; ++qi)
#pragma unroll
            for (int pi = 0; pi < 2; ++pi)
#pragma unroll
                for (int r = 0; r < 16; ++r) {
                    float s = acc1[pi][qi][r] + acc2[pi][qi][r] * (1.0f / 2048.0f);
                    int code = kb + wp * 64 + pi * 32 + (r & 3) + ((r >> 2) << 3) + (half << 2);
                    uint32_t u = __float_as_uint(s);
                    u = (u & 0x80000000u) ? ~u : (u | 0x80000000u);
                    unsigned long long key = ((unsigned long long)u << 32) | (unsigned long long)(unsigned)code;
                    if (key < best[qi]) best[qi] = key;
                }
    }  // col

#pragma unroll
    for (int qi = 0; qi < 2; ++qi) {
        unsigned long long o = __shfl_xor(best[qi], 32, 64);
        if (o < best[qi]) best[qi] = o;
        if (half == 0) {
            int token = n0 + wq * 64 + qi * 32 + l31;
            atomicMin(&wmin[token], best[qi]);
        }
    }
}

__global__ void gather_kernel(const float* __restrict__ z, const float* __restrict__ cb,
                              const unsigned long long* __restrict__ wmin,
                              float* __restrict__ out, int* __restrict__ counts,
                              float* __restrict__ sse_acc) {
    __shared__ unsigned int sIdx[64];
    __shared__ float red[4];
    const int tid = threadIdx.x;
    const int n0 = blockIdx.x * 64;
    const int b = n0 >> 8;
    const int t0 = n0 & 255;
    if (tid < 64) {
        unsigned int idx = (unsigned int)(wmin[n0 + tid] & 0xffffffffULL);
        sIdx[tid] = idx;
        atomicAdd(&counts[idx], 1);
    }
    __syncthreads();
    const int w = tid >> 6;
    const int lane = tid & 63;
    const float* crow = cb + (size_t)sIdx[lane] * EMBED_DIM;
    const size_t base = ((size_t)b * EMBED_DIM) * T_ + (size_t)(t0 + lane);
    float sse = 0.f;
    for (int d = w; d < EMBED_DIM; d += 4) {
        float v = crow[d];
        size_t o = base + (size_t)d * T_;
        float diff = v - z[o];
        out[o] = v;  // z + sg(z_q - z) == z_q numerically
        sse += diff * diff;
    }
    for (int m = 32; m; m >>= 1) sse += __shfl_xor(sse, m, 64);
    if (lane == 0) red[w] = sse;
    __syncthreads();
    if (tid == 0) atomicAdd(sse_acc, red[0] + red[1] + red[2] + red[3]);
}

__global__ void finalize_kernel(const int* __restrict__ counts,
                                const float* __restrict__ sse_acc,
                                float* __restrict__ out) {
    __shared__ float red[4];
    const int tid = threadIdx.x;
    float e = 0.f;
    for (int k = tid; k < NUM_EMBEDS; k += 256) {
        float p = (float)counts[k] * (1.0f / (float)N_TOK);
        e += p * logf(p + 1e-10f);
    }
    for (int m = 32; m; m >>= 1) e += __shfl_xor(e, m, 64);
    if ((tid & 63) == 0) red[tid >> 6] = e;
    __syncthreads();
    if (tid == 0) {
        float ent = red[0] + red[1] + red[2] + red[3];
        size_t off = (size_t)B_ * EMBED_DIM * T_;
        out[off + 0] = (ALPHA_ * BETA_) * sse_acc[0] / (float)((size_t)N_TOK * EMBED_DIM);
        out[off + 1] = expf(-ent);
    }
}

extern "C" void kernel_launch(void* const* d_in, const int* in_sizes, int n_in,
                              void* d_out, int out_size, void* d_ws, size_t ws_size,
                              hipStream_t stream) {
    const float* z = (const float*)d_in[0];
    const float* cb = (const float*)d_in[1];
    float* out = (float*)d_out;
    char* ws = (char*)d_ws;
    unsigned long long* wmin = (unsigned long long*)ws;
    float* cnorm = (float*)(ws + 65536);
    int* counts = (int*)(ws + 98304);
    float* sse = (float*)(ws + 131072);

    hipMemsetAsync(wmin, 0xFF, NUM_EMBEDS * sizeof(unsigned long long), stream);
    hipMemsetAsync(counts, 0, NUM_EMBEDS * sizeof(int) + sizeof(float), stream);  // counts + sse

    cnorm_kernel<<<NUM_EMBEDS / 4, 256, 0, stream>>>(cb, cnorm);
    argmin_kernel<<<dim3(N_TOK / TN_BLK, KSPLIT), 256, 0, stream>>>(z, cb, cnorm, wmin);
    gather_kernel<<<N_TOK / 64, 256, 0, stream>>>(z, cb, wmin, out, counts, sse);
    finalize_kernel<<<1, 256, 0, stream>>>(counts, sse, out);
}

// Round 3
// 427.133 us; speedup vs baseline: 2.2098x; 1.0198x over previous
//
#include <hip/hip_runtime.h>
#include <stdint.h>

typedef _Float16 half8 __attribute__((ext_vector_type(8)));
typedef float floatx16 __attribute__((ext_vector_type(16)));

#define ALPHA_ 1.0f
#define BETA_ 0.25f
#define NUM_EMBEDS 8192
#define EMBED_DIM 512
#define B_ 32
#define T_ 256
#define N_TOK 8192

// ---------------- ws layout (bytes) ----------------
// wmin   @ 0        (64 KB)  packed min: key<<32 | idx
// cnorm  @ 65536    (32 KB)
// counts @ 98304    (32 KB)
// sse    @ 131072   (4 B)
// cb_h   @ 1  MB    (8 MB)   f16 high plane of codebook [k][d]
// cb_m   @ 9  MB    (8 MB)   f16 (x-h)*2048 plane
// zt_h   @ 17 MB    (8 MB)   f16 high plane of -2*z, transposed [n][d]
// zt_m   @ 25 MB    (8 MB)
// ---------------------------------------------------

typedef __attribute__((address_space(1))) const void ga_void;
typedef __attribute__((address_space(3))) void ls_void;
__device__ __forceinline__ void gl_lds16(const void* g, void* l) {
    __builtin_amdgcn_global_load_lds((ga_void*)g, (ls_void*)l, 16, 0, 0);
}

// pack codebook into 2 f16 planes + row norms (fused cnorm)
__global__ void pack_cb_kernel(const float* __restrict__ cb, _Float16* __restrict__ h,
                               _Float16* __restrict__ m, float* __restrict__ cnorm) {
    int row = blockIdx.x * 4 + (threadIdx.x >> 6);
    int lane = threadIdx.x & 63;
    const float* src = cb + (size_t)row * EMBED_DIM + lane * 8;
    float4 v0 = *(const float4*)src;
    float4 v1 = *(const float4*)(src + 4);
    float x[8] = {v0.x, v0.y, v0.z, v0.w, v1.x, v1.y, v1.z, v1.w};
    half8 hh, mm;
    float s = 0.f;
#pragma unroll
    for (int j = 0; j < 8; ++j) {
        s += x[j] * x[j];
        _Float16 hv = (_Float16)x[j];
        hh[j] = hv;
        mm[j] = (_Float16)((x[j] - (float)hv) * 2048.0f);
    }
    *(half8*)(h + (size_t)row * EMBED_DIM + lane * 8) = hh;
    *(half8*)(m + (size_t)row * EMBED_DIM + lane * 8) = mm;
#pragma unroll
    for (int d = 32; d; d >>= 1) s += __shfl_xor(s, d, 64);
    if (lane == 0) cnorm[row] = s;
}

// transpose z (b,d,t) -> (n=b*T+t, d) and pack -2*z into 2 f16 planes
__global__ void pack_z_kernel(const float* __restrict__ z, _Float16* __restrict__ h,
                              _Float16* __restrict__ m) {
    int tid = threadIdx.x;
    int lane = tid & 63, ds = tid >> 6;
    int b = blockIdx.x >> 2;
    int t = ((blockIdx.x & 3) << 6) + lane;
    size_t n = (size_t)b * T_ + t;
    for (int g = 0; g < 16; ++g) {
        int d0 = g * 32 + ds * 8;
        const float* src = z + ((size_t)b * EMBED_DIM + d0) * T_ + t;
        half8 hh, mm;
#pragma unroll
        for (int j = 0; j < 8; ++j) {
            float x = -2.0f * src[(size_t)j * T_];
            _Float16 hv = (_Float16)x;
            hh[j] = hv;
            mm[j] = (_Float16)((x - (float)hv) * 2048.0f);
        }
        *(half8*)(h + n * EMBED_DIM + d0) = hh;
        *(half8*)(m + n * EMBED_DIM + d0) = mm;
    }
}

// ---- argmin GEMM: 128 codes x 128 tokens per block, pipelined K-loop ----
__global__ __launch_bounds__(256, 2) void argmin_kernel(
    const _Float16* __restrict__ cb_h, const _Float16* __restrict__ cb_m,
    const _Float16* __restrict__ zt_h, const _Float16* __restrict__ zt_m,
    const float* __restrict__ cnorm, unsigned long long* __restrict__ wmin) {
    // 4 regions of 2048 halves: Ah, Am, Bh, Bm; each [128 rows][16 k], unpadded
    __shared__ _Float16 smem[8192];
    const int tid = threadIdx.x;
    const int lane = tid & 63;
    const int wv = tid >> 6;
    const int l31 = lane & 31;
    const int hf = lane >> 5;
    const int wp = wv >> 1, wq = wv & 1;
    const int n0 = blockIdx.x * 128;
    const int kbase = blockIdx.y * 1024;

    // each wave stages its own region: 0:Ah 1:Am 2:Bh 3:Bm
    const _Float16* gplane = (wv == 0) ? cb_h : (wv == 1) ? cb_m : (wv == 2) ? zt_h : zt_m;
    const size_t gbase0 = ((wv < 2) ? (size_t)kbase : (size_t)n0) * EMBED_DIM +
                          (size_t)(lane >> 1) * EMBED_DIM + (size_t)(lane & 1) * 8;
    _Float16* lreg = &smem[wv * 2048];

    const int fro = l31 * 16 + hf * 8;  // fragment offset within a region (halves)

    unsigned long long best0 = ~0ULL, best1 = ~0ULL;

    for (int col = 0; col < 8; ++col) {
        const int kb = kbase + (col << 7);
        const _Float16* g = gplane + gbase0 + ((wv < 2) ? (size_t)(col << 7) * EMBED_DIM : 0);

        floatx16 acc1[2][2], acc2[2][2];
#pragma unroll
        for (int pi = 0; pi < 2; ++pi)
#pragma unroll
            for (int qi = 0; qi < 2; ++qi)
#pragma unroll
                for (int r = 0; r < 16; ++r) { acc1[pi][qi][r] = 0.f; acc2[pi][qi][r] = 0.f; }

        // prologue: stage d0 = 0
#pragma unroll
        for (int i = 0; i < 4; ++i)
            gl_lds16(g + (size_t)(i * 32) * EMBED_DIM, lreg + i * 512);
        __syncthreads();

        for (int step = 0; step < 32; ++step) {
            half8 Ah[2], Am[2], Bh[2], Bm[2];
#pragma unroll
            for (int pi = 0; pi < 2; ++pi) {
                Ah[pi] = *(const half8*)&smem[(wp << 10) + (pi << 9) + fro];
                Am[pi] = *(const half8*)&smem[2048 + (wp << 10) + (pi << 9) + fro];
            }
#pragma unroll
            for (int qi = 0; qi < 2; ++qi) {
                Bh[qi] = *(const half8*)&smem[4096 + (wq << 10) + (qi << 9) + fro];
                Bm[qi] = *(const half8*)&smem[6144 + (wq << 10) + (qi << 9) + fro];
            }
            __syncthreads();  // all frag reads done before anyone's async loads land
            if (step < 31) {
                const _Float16* gs = g + ((step + 1) << 4);
#pragma unroll
                for (int i = 0; i < 4; ++i)
                    gl_lds16(gs + (size_t)(i * 32) * EMBED_DIM, lreg + i * 512);
            }
#pragma unroll
            for (int pi = 0; pi < 2; ++pi)
#pragma unroll
                for (int qi = 0; qi < 2; ++qi) {
                    acc1[pi][qi] = __builtin_amdgcn_mfma_f32_32x32x16_f16(Ah[pi], Bh[qi], acc1[pi][qi], 0, 0, 0);
                    acc2[pi][qi] = __builtin_amdgcn_mfma_f32_32x32x16_f16(Ah[pi], Bm[qi], acc2[pi][qi], 0, 0, 0);
                    acc2[pi][qi] = __builtin_amdgcn_mfma_f32_32x32x16_f16(Am[pi], Bh[qi], acc2[pi][qi], 0, 0, 0);
                }
            __syncthreads();  // vmcnt(0) drain here is hidden behind the MFMAs above
        }

        // epilogue: score = cnorm[code] + acc1 + acc2/2048, fold into running best
#pragma unroll
        for (int pi = 0; pi < 2; ++pi)
#pragma unroll
            for (int r = 0; r < 16; ++r) {
                int code = kb + (wp << 6) + (pi << 5) + (r & 3) + ((r >> 2) << 3) + (hf << 2);
                float cnv = cnorm[code];
                {
                    float s = cnv + acc1[pi][0][r] + acc2[pi][0][r] * (1.0f / 2048.0f);
                    uint32_t u = __float_as_uint(s);
                    u = (u & 0x80000000u) ? ~u : (u | 0x80000000u);
                    unsigned long long key = ((unsigned long long)u << 32) | (unsigned)code;
                    if (key < best0) best0 = key;
                }
                {
                    float s = cnv + acc1[pi][1][r] + acc2[pi][1][r] * (1.0f / 2048.0f);
                    uint32_t u = __float_as_uint(s);
                    u = (u & 0x80000000u) ? ~u : (u | 0x80000000u);
                    unsigned long long key = ((unsigned long long)u << 32) | (unsigned)code;
                    if (key < best1) best1 = key;
                }
            }
    }

    // cross-half reduce (lane vs lane^32 hold same token), then atomic
    {
        unsigned long long o = __shfl_xor(best0, 32, 64);
        if (o < best0) best0 = o;
        o = __shfl_xor(best1, 32, 64);
        if (o < best1) best1 = o;
        if (hf == 0) {
            atomicMin(&wmin[n0 + (wq << 6) + l31], best0);
            atomicMin(&wmin[n0 + (wq << 6) + 32 + l31], best1);
        }
    }
}

__global__ void gather_kernel(const float* __restrict__ z, const float* __restrict__ cb,
                              const unsigned long long* __restrict__ wmin,
                              float* __restrict__ out, int* __restrict__ counts,
                              float* __restrict__ sse_acc) {
    __shared__ unsigned int sIdx[64];
    __shared__ float red[4];
    const int tid = threadIdx.x;
    const int n0 = blockIdx.x * 64;
    const int b = n0 >> 8;
    const int t0 = n0 & 255;
    if (tid < 64) {
        unsigned int idx = (unsigned int)(wmin[n0 + tid] & 0xffffffffULL);
        sIdx[tid] = idx;
        atomicAdd(&counts[idx], 1);
    }
    __syncthreads();
    const int w = tid >> 6;
    const int lane = tid & 63;
    const float* crow = cb + (size_t)sIdx[lane] * EMBED_DIM;
    const size_t base = ((size_t)b * EMBED_DIM) * T_ + (size_t)(t0 + lane);
    float sse = 0.f;
    for (int d = w; d < EMBED_DIM; d += 4) {
        float v = crow[d];
        size_t o = base + (size_t)d * T_;
        float diff = v - z[o];
        out[o] = v;  // z + sg(z_q - z) == z_q numerically
        sse += diff * diff;
    }
    for (int m = 32; m; m >>= 1) sse += __shfl_xor(sse, m, 64);
    if (lane == 0) red[w] = sse;
    __syncthreads();
    if (tid == 0) atomicAdd(sse_acc, red[0] + red[1] + red[2] + red[3]);
}

__global__ void finalize_kernel(const int* __restrict__ counts,
                                const float* __restrict__ sse_acc,
                                float* __restrict__ out) {
    __shared__ float red[4];
    const int tid = threadIdx.x;
    float e = 0.f;
    for (int k = tid; k < NUM_EMBEDS; k += 256) {
        float p = (float)counts[k] * (1.0f / (float)N_TOK);
        e += p * logf(p + 1e-10f);
    }
    for (int m = 32; m; m >>= 1) e += __shfl_xor(e, m, 64);
    if ((tid & 63) == 0) red[tid >> 6] = e;
    __syncthreads();
    if (tid == 0) {
        float ent = red[0] + red[1] + red[2] + red[3];
        size_t off = (size_t)B_ * EMBED_DIM * T_;
        out[off + 0] = (ALPHA_ * BETA_) * sse_acc[0] / (float)((size_t)N_TOK * EMBED_DIM);
        out[off + 1] = expf(-ent);
    }
}

extern "C" void kernel_launch(void* const* d_in, const int* in_sizes, int n_in,
                              void* d_out, int out_size, void* d_ws, size_t ws_size,
                              hipStream_t stream) {
    const float* z = (const float*)d_in[0];
    const float* cb = (const float*)d_in[1];
    float* out = (float*)d_out;
    char* ws = (char*)d_ws;
    unsigned long long* wmin = (unsigned long long*)ws;
    float* cnorm = (float*)(ws + 65536);
    int* counts = (int*)(ws + 98304);
    float* sse = (float*)(ws + 131072);
    _Float16* cb_h = (_Float16*)(ws + (1ull << 20));
    _Float16* cb_m = (_Float16*)(ws + (9ull << 20));
    _Float16* zt_h = (_Float16*)(ws + (17ull << 20));
    _Float16* zt_m = (_Float16*)(ws + (25ull << 20));

    hipMemsetAsync(wmin, 0xFF, NUM_EMBEDS * sizeof(unsigned long long), stream);
    hipMemsetAsync(counts, 0, NUM_EMBEDS * sizeof(int) + sizeof(float), stream);  // counts + sse

    pack_cb_kernel<<<NUM_EMBEDS / 4, 256, 0, stream>>>(cb, cb_h, cb_m, cnorm);
    pack_z_kernel<<<(B_ * T_) / 64, 256, 0, stream>>>(z, zt_h, zt_m);
    argmin_kernel<<<dim3(N_TOK / 128, NUM_EMBEDS / 1024), 256, 0, stream>>>(cb_h, cb_m, zt_h, zt_m, cnorm, wmin);
    gather_kernel<<<N_TOK / 64, 256, 0, stream>>>(z, cb, wmin, out, counts, sse);
    finalize_kernel<<<1, 256, 0, stream>>>(counts, sse, out);
}